// Round 4
// baseline (6064.286 us; speedup 1.0000x reference)
//
#include <hip/hip_runtime.h>
#include <cstdint>
#include <cstddef>

// GRU decoder: LAYERS=3, UNITS=1024, B=128, T=256, reset_after=True.
// R5: persistent per-layer recurrence, MALL-coherent (sc0 sc1) exchange.
// vs R4: (a) sync via one atomic counter per (rg,t) + broadcast single-dword
// poll (was 32x16B poll requests/wave/iter); (b) B-fragments kk0-15 pinned in
// registers across all 256 steps (192 VGPRs) -> LDS stream per step halved.

#define UNITS 1024
#define U3 3072
#define BATCH 128
#define TSTEPS 256

typedef _Float16 h16;
typedef __attribute__((ext_vector_type(8))) _Float16 h16x8;
typedef __attribute__((ext_vector_type(4))) _Float16 h16x4;
typedef __attribute__((ext_vector_type(4))) float f32x4;
typedef __attribute__((ext_vector_type(4))) unsigned int u32x4;

#define GAS __attribute__((address_space(1)))
#define LAS __attribute__((address_space(3)))
#define ASYNC16(g, l) __builtin_amdgcn_global_load_lds((const GAS unsigned int*)(g), (LAS unsigned int*)(l), 16, 0, 0)

__device__ __forceinline__ float sigmf(float x) { return 1.0f / (1.0f + __expf(-x)); }
__device__ __forceinline__ float tanhf_fast(float x) { return 2.0f / (1.0f + __expf(-2.0f * x)) - 1.0f; }

// input_seq [B,T,U] f32 -> x16 [T,B,U] f16  (t-major so per-step slices are contiguous)
__global__ void k_cvt_x(const float* __restrict__ x, h16* __restrict__ xo) {
  const int m = blockIdx.x;            // out row = t*128 + b
  const int t = m >> 7, b = m & 127;
  const int u = threadIdx.x << 2;
  const float4 v = *(const float4*)(x + (size_t)((b << 8) + t) * UNITS + u);
  h16x4 o; o[0] = (h16)v.x; o[1] = (h16)v.y; o[2] = (h16)v.z; o[3] = (h16)v.w;
  *(h16x4*)(xo + (size_t)m * UNITS + u) = o;
}

// src [3][1024][3072] f32 -> dst [3][3072][1024] f16 (transpose: K-contiguous "B^T" layout)
__global__ void k_trans(const float* __restrict__ src, h16* __restrict__ dst) {
  __shared__ float sT[32][33];
  const int l = blockIdx.z;
  const int n0 = blockIdx.x << 5, k0 = blockIdx.y << 5;
  const int tx = threadIdx.x, ty = threadIdx.y;   // 32 x 8
  const float* s = src + (size_t)l * UNITS * U3;
  h16* d = dst + (size_t)l * U3 * UNITS;
#pragma unroll
  for (int r = 0; r < 4; ++r)
    sT[ty + r * 8][tx] = s[(size_t)(k0 + ty + r * 8) * U3 + n0 + tx];
  __syncthreads();
#pragma unroll
  for (int r = 0; r < 4; ++r)
    d[(size_t)(n0 + ty + r * 8) * UNITS + k0 + tx] = (h16)sT[tx][ty + r * 8];
}

// initial_states [B,U,3] f32 -> h0 [3][B*U] f16
__global__ void k_cvt_h(const float* __restrict__ init, h16* __restrict__ h0) {
  const int idx = blockIdx.x * 256 + threadIdx.x;  // < 3*131072
  const int l = idx >> 17, r = idx & 131071;
  h0[idx] = (h16)init[(size_t)r * 3 + l];
}

__global__ void k_zero(int* __restrict__ p, int n) {
  const int i = blockIdx.x * 256 + threadIdx.x;
  if (i < n) p[i] = 0;
}

// C[M,3072] = A[M,1024] @ Bt[3072,1024]^T + bias  (all f16 in, f32 acc, f16 out)
// m97 structure: 128x128 tile, BK=32, 4 waves 2x2, global_load_lds width 16.
__global__ __launch_bounds__(256) void k_gemm_xw(
    const h16* __restrict__ A, const h16* __restrict__ Bt,
    const float* __restrict__ bias, h16* __restrict__ C) {
  __shared__ __align__(16) h16 sA[128 * 32];
  __shared__ __align__(16) h16 sB[128 * 32];
  const int tid = threadIdx.x;
  const int lane = tid & 63, wave = tid >> 6;
  const int wm = (wave & 1) << 6, wn = (wave >> 1) << 6;
  const int m0 = blockIdx.x << 7;
  const int n0 = blockIdx.y << 7;
  const int crow = tid >> 2, ck = (tid & 3) << 3;
  const int fm = lane & 15, fq = lane >> 4;
  f32x4 acc[4][4] = {};
  for (int k0 = 0; k0 < 1024; k0 += 32) {
    ASYNC16(A + (size_t)(m0 + crow) * 1024 + k0 + ck,      sA + wave * 512);
    ASYNC16(A + (size_t)(m0 + 64 + crow) * 1024 + k0 + ck, sA + 2048 + wave * 512);
    ASYNC16(Bt + (size_t)(n0 + crow) * 1024 + k0 + ck,      sB + wave * 512);
    ASYNC16(Bt + (size_t)(n0 + 64 + crow) * 1024 + k0 + ck, sB + 2048 + wave * 512);
    __syncthreads();
    h16x8 af[4], bfv[4];
#pragma unroll
    for (int i = 0; i < 4; ++i)
      af[i] = *(const h16x8*)(sA + (wm + i * 16 + fm) * 32 + fq * 8);
#pragma unroll
    for (int j = 0; j < 4; ++j)
      bfv[j] = *(const h16x8*)(sB + (wn + j * 16 + fm) * 32 + fq * 8);
#pragma unroll
    for (int i = 0; i < 4; ++i)
#pragma unroll
      for (int j = 0; j < 4; ++j)
        acc[i][j] = __builtin_amdgcn_mfma_f32_16x16x32_f16(af[i], bfv[j], acc[i][j], 0, 0, 0);
    __syncthreads();
  }
#pragma unroll
  for (int j = 0; j < 4; ++j) {
    const int col = n0 + wn + j * 16 + fm;
    const float bv = bias[col];
#pragma unroll
    for (int i = 0; i < 4; ++i) {
      const int row = m0 + wm + i * 16 + fq * 4;
#pragma unroll
      for (int r = 0; r < 4; ++r)
        C[(size_t)(row + r) * U3 + col] = (h16)(acc[i][j][r] + bv);
    }
  }
}

// Persistent recurrence kernel: one launch per layer, all 256 steps inside.
// 256 blocks x 128 threads (2 waves, decoupled). Block b: col-group c=b&63
// (16 h-cols), row-group rg=b>>6 (32 rows); wave w owns 16 rows.
// U^T slice (96KB) staged to LDS once; kk=0..15 B-frags then pinned in VGPRs
// (192 regs) for all 256 steps; kk=16..31 read from LDS per step.
// Sync: producers lane0-atomic_add cnt[rg][t] (device scope, at MALL);
// consumers poll with a single broadcast sc0sc1 dword load. h via sc0sc1.
__global__ __launch_bounds__(128, 1) void k_rec(
    const h16* __restrict__ Ut,     // [3072][1024] this layer
    const float* __restrict__ b1,   // [3072] recurrent bias
    const h16* __restrict__ xw,     // [T*128][3072]
    const h16* __restrict__ h0l,    // [128][1024] initial state
    h16* __restrict__ P0,           // ping buffer [128][1024]
    h16* __restrict__ P1,           // pong buffer [128][1024]
    h16* __restrict__ y16,          // x16 base ([T][128][1024]) or null
    float* __restrict__ yf,         // f32 out y region or null (layer 2)
    float* __restrict__ st,         // d_out states + l (stride 3)
    int* __restrict__ cnt,          // [4][256] step counters (see launch)
    const int tgt) {                // poll target = (layers done here)*128
  __shared__ __align__(16) h16 sU[49152];   // 96KB: [32 kk][3 g][64 lane][8]
  const int tid = threadIdx.x;
  const int lane = tid & 63, w = tid >> 6;
  const int b = blockIdx.x;
  const int c = b & 63, rg = b >> 6;
  const int c0 = c << 4;
  const int fm = lane & 15, fq = lane >> 4;

  // ---- stage U^T slice into LDS once ----
#pragma unroll
  for (int kk = 0; kk < 32; ++kk) {
#pragma unroll
    for (int g = 0; g < 3; ++g) {
      const int i = kk * 3 + g;
      if ((i & 1) == w)
        ASYNC16(Ut + (size_t)((g << 10) + c0 + fm) * 1024 + (kk << 5) + (fq << 3),
                sU + (size_t)i * 512);
    }
  }
  const int col = c0 + fm;
  const float bz = b1[col], br = b1[1024 + col], bh = b1[2048 + col];
  const int r0 = (rg << 5) + (w << 4);     // wave's first row
  const int rowA = r0 + fm;                // A-frag row for this lane
  const int rQ = r0 + (fq << 2);           // first of this lane's 4 C-rows
  int* cbase = cnt + (rg << 8);
  __syncthreads();                          // drains ASYNC16 vmcnt both waves

  // ---- pin kk=0..15 B-fragments in registers for the whole layer ----
  h16x8 Bz[16], Br[16], Bh[16];
#pragma unroll
  for (int kk = 0; kk < 16; ++kk) {
    const h16* bb = sU + (size_t)(kk * 3) * 512 + (lane << 3);
    Bz[kk] = *(const h16x8*)(bb);
    Br[kk] = *(const h16x8*)(bb + 512);
    Bh[kk] = *(const h16x8*)(bb + 1024);
  }

  for (int t = 0; t < TSTEPS; ++t) {
    // ---- wait for own row-group's previous step: broadcast counter poll ----
    if (t > 0) {
      const int* cp = cbase + t - 1;
      int f;
      do {
        asm volatile("global_load_dword %0, %1, off sc0 sc1\n\ts_waitcnt vmcnt(0)"
                     : "=v"(f) : "v"(cp) : "memory");
      } while (f < tgt);
    }
    const h16* hin = (t == 0) ? h0l : ((t & 1) ? P0 : P1);
    h16* hout = (t & 1) ? P1 : P0;

    // ---- issue exactly 48 loads: 32 A (MALL), 4 hp (MALL), 12 xw (HBM) ----
    u32x4 raw[32];
    const h16* Ab = hin + (size_t)rowA * 1024 + (fq << 3);
#pragma unroll
    for (int kk = 0; kk < 32; ++kk)
      asm volatile("global_load_dwordx4 %0, %1, off offset:%2 sc0 sc1"
                   : "=v"(raw[kk]) : "v"(Ab), "n"(kk * 64));
    unsigned int hpu[4];
    const h16* hqa = hin + (size_t)rQ * 1024 + col;
    const h16* hqb = hqa + 2048;  // +2 rows (13-bit signed imm caps at 4095)
    asm volatile("global_load_ushort %0, %1, off sc0 sc1"             : "=v"(hpu[0]) : "v"(hqa));
    asm volatile("global_load_ushort %0, %1, off offset:2048 sc0 sc1" : "=v"(hpu[1]) : "v"(hqa));
    asm volatile("global_load_ushort %0, %1, off sc0 sc1"             : "=v"(hpu[2]) : "v"(hqb));
    asm volatile("global_load_ushort %0, %1, off offset:2048 sc0 sc1" : "=v"(hpu[3]) : "v"(hqb));
    unsigned int xwb[12];
    {
      const h16* xq = xw + (size_t)(t * 128 + rQ) * U3 + col;
#pragma unroll
      for (int r = 0; r < 4; ++r) {
        const h16* xa = xq + (size_t)r * U3;
        const h16* xb2 = xa + 2048;
        asm volatile("global_load_ushort %0, %1, off"             : "=v"(xwb[r * 3 + 0]) : "v"(xa));
        asm volatile("global_load_ushort %0, %1, off offset:2048" : "=v"(xwb[r * 3 + 1]) : "v"(xa));
        asm volatile("global_load_ushort %0, %1, off"             : "=v"(xwb[r * 3 + 2]) : "v"(xb2));
      }
    }

    // ---- K-loop: 4 chunks of 8 kk, gated on A arrival by counted vmcnt.
    //      kk 0..15: B from pinned regs; kk 16..31: B from LDS. ----
    f32x4 a0 = {}, a1 = {}, a2 = {};
#pragma unroll
    for (int ch = 0; ch < 4; ++ch) {
      if (ch == 0) asm volatile("s_waitcnt vmcnt(40)" ::: "memory");
      if (ch == 1) asm volatile("s_waitcnt vmcnt(32)" ::: "memory");
      if (ch == 2) asm volatile("s_waitcnt vmcnt(24)" ::: "memory");
      if (ch == 3) asm volatile("s_waitcnt vmcnt(16)" ::: "memory");
      __builtin_amdgcn_sched_barrier(0);   // rule #18: keep MFMA below the wait
#pragma unroll
      for (int kk = ch * 8; kk < ch * 8 + 8; ++kk) {
        union { u32x4 u; h16x8 h; } ac; ac.u = raw[kk];
        if (kk < 16) {
          a0 = __builtin_amdgcn_mfma_f32_16x16x32_f16(ac.h, Bz[kk], a0, 0, 0, 0);
          a1 = __builtin_amdgcn_mfma_f32_16x16x32_f16(ac.h, Br[kk], a1, 0, 0, 0);
          a2 = __builtin_amdgcn_mfma_f32_16x16x32_f16(ac.h, Bh[kk], a2, 0, 0, 0);
        } else {
          const h16* bb = sU + (size_t)(kk * 3) * 512 + (lane << 3);
          const h16x8 vz = *(const h16x8*)(bb);
          const h16x8 vr = *(const h16x8*)(bb + 512);
          const h16x8 vh = *(const h16x8*)(bb + 1024);
          a0 = __builtin_amdgcn_mfma_f32_16x16x32_f16(ac.h, vz, a0, 0, 0, 0);
          a1 = __builtin_amdgcn_mfma_f32_16x16x32_f16(ac.h, vr, a1, 0, 0, 0);
          a2 = __builtin_amdgcn_mfma_f32_16x16x32_f16(ac.h, vh, a2, 0, 0, 0);
        }
      }
    }
    asm volatile("s_waitcnt vmcnt(0)" ::: "memory");   // hp + xw arrived
    __builtin_amdgcn_sched_barrier(0);

    // ---- gates + protocol stores (C/D: col=lane&15, row=(lane>>4)*4+r) ----
    h16* so = hout + (size_t)rQ * 1024 + col;
    float hn[4];
#pragma unroll
    for (int r = 0; r < 4; ++r) {
      union { unsigned short s; h16 h; } cv;
      cv.s = (unsigned short)hpu[r];         const float hp = (float)cv.h;
      cv.s = (unsigned short)xwb[r * 3 + 0]; const float xz = (float)cv.h;
      cv.s = (unsigned short)xwb[r * 3 + 1]; const float xr = (float)cv.h;
      cv.s = (unsigned short)xwb[r * 3 + 2]; const float xh = (float)cv.h;
      const float z   = sigmf(xz + a0[r] + bz);
      const float rgt = sigmf(xr + a1[r] + br);
      const float hh  = tanhf_fast(xh + rgt * (a2[r] + bh));
      hn[r] = z * hp + (1.0f - z) * hh;
      union { unsigned short s; h16 h; } ov; ov.h = (h16)hn[r];
      const unsigned int ob = ov.s;
      if (r == 0) asm volatile("global_store_short %0, %1, off sc0 sc1"             :: "v"(so), "v"(ob) : "memory");
      if (r == 1) asm volatile("global_store_short %0, %1, off offset:2048 sc0 sc1" :: "v"(so), "v"(ob) : "memory");
      if (r == 2) asm volatile("global_store_short %0, %1, off sc0 sc1"             :: "v"(so + 2048), "v"(ob) : "memory");
      if (r == 3) asm volatile("global_store_short %0, %1, off offset:2048 sc0 sc1" :: "v"(so + 2048), "v"(ob) : "memory");
    }
    asm volatile("s_waitcnt vmcnt(0)" ::: "memory");   // h landed at MALL
    if (lane == 0)
      (void)__hip_atomic_fetch_add(cbase + t, 1, __ATOMIC_RELAXED,
                                   __HIP_MEMORY_SCOPE_AGENT);
    // ---- non-protocol stores AFTER the post (drained by next poll) ----
#pragma unroll
    for (int r = 0; r < 4; ++r) {
      const int row = rQ + r;
      if (y16) y16[(size_t)(t * 128 + row) * 1024 + col] = (h16)hn[r];
      if (yf)  yf[(size_t)(row * 256 + t) * 1024 + col] = hn[r];
      if (t == 255) st[(size_t)(row * 1024 + col) * 3] = hn[r];
    }
  }
}

extern "C" void kernel_launch(void* const* d_in, const int* in_sizes, int n_in,
                              void* d_out, int out_size, void* d_ws, size_t ws_size,
                              hipStream_t stream) {
  const float* x_in  = (const float*)d_in[0];   // [128,256,1024]
  const float* h0_in = (const float*)d_in[1];   // [128,1024,3]
  const float* W     = (const float*)d_in[2];   // [3,1024,3072]
  const float* U     = (const float*)d_in[3];   // [3,1024,3072]
  const float* bias  = (const float*)d_in[4];   // [3,2,3072]
  float* out = (float*)d_out;

  char* ws = (char*)d_ws;
  h16* x16 = (h16*)(ws);                         // 67,108,864 B   [T,B,U]
  h16* xw  = (h16*)(ws + 67108864);              // 201,326,592 B  [T,B,3U]
  h16* Wt  = (h16*)(ws + 268435456);             // 18,874,368 B   [3][3072][1024]
  h16* Ut  = (h16*)(ws + 287309824);             // 18,874,368 B   [3][3072][1024]
  h16* h0b = (h16*)(ws + 306184192);             // 786,432 B      [3][128*1024]
  h16* P0  = (h16*)(ws + 306970624);             // 262,144 B      ping buffer

  // Scratch carved from dead regions (ws footprint unchanged):
  //  layers 0,1: pong buffer + counters live in the tail of the f32 y-output
  //  (only written by layer 2 at the end of its own stepping -> dead here).
  //  Counters accumulate across layers 0,1 (targets 128/256 -> no re-zero).
  //  layer 2: pong buffer + counters live in x16 (consumed by its GEMM).
  h16* P1A   = (h16*)((char*)d_out + 134217728 - 262144);
  int* cntA  = (int*)((char*)d_out + 134217728 - 262144 - 16384);
  h16* P1B   = (h16*)ws;                         // x16 base, dead during l=2
  int* cntB  = (int*)(ws + 262144);              // x16+256KB, dead during l=2

  k_cvt_x<<<TSTEPS * BATCH, 256, 0, stream>>>(x_in, x16);
  k_trans<<<dim3(96, 32, 3), dim3(32, 8), 0, stream>>>(W, Wt);
  k_trans<<<dim3(96, 32, 3), dim3(32, 8), 0, stream>>>(U, Ut);
  k_cvt_h<<<1536, 256, 0, stream>>>(h0_in, h0b);
  k_zero<<<4, 256, 0, stream>>>(cntA, 1024);

  for (int l = 0; l < 3; ++l) {
    const float* b0 = bias + (size_t)l * 6144;
    const float* b1 = bias + (size_t)l * 6144 + 3072;
    k_gemm_xw<<<dim3(256, 24), 256, 0, stream>>>(x16, Wt + (size_t)l * U3 * UNITS, b0, xw);
    if (l == 2) k_zero<<<4, 256, 0, stream>>>(cntB, 1024);
    h16* P1   = (l < 2) ? P1A : P1B;
    int* cnt  = (l < 2) ? cntA : cntB;
    const int tgt = (l < 2) ? (l + 1) * 128 : 128;   // posts visible per step
    h16* y16p  = (l < 2) ? x16 : nullptr;
    float* yfp = (l == 2) ? out : nullptr;
    float* stp = out + 33554432 + l;
    k_rec<<<256, 128, 0, stream>>>(Ut + (size_t)l * U3 * UNITS, b1, xw,
                                   h0b + (size_t)l * BATCH * UNITS,
                                   P0, P1, y16p, yfp, stp, cnt, tgt);
  }
}

// Round 5
// 5993.087 us; speedup vs baseline: 1.0119x; 1.0119x over previous
//
#include <hip/hip_runtime.h>
#include <cstdint>
#include <cstddef>

// GRU decoder: LAYERS=3, UNITS=1024, B=128, T=256, reset_after=True.
// R6: persistent per-layer recurrence. Fixes vs R5:
//  (1) protocol ops at AGENT scope (sc1 only) -- R3-R5 used sc0+sc1 = SYSTEM
//      scope (SC[1:0]=3), forcing every sync/bulk op past the MALL.
//  (2) h ping-pong -> rolling history buffer IN x16 (slot s = h_s = y[s]):
//      fresh addresses each step => consumer A-reads are PLAIN cached loads
//      (L2-shared within XCD, 8x traffic cut); one fence(acquire,agent) per
//      block at entry kills pre-epoch stale lines. y16 dup stores gone.
//  (3) xw gate pre-activations prefetched cross-step into registers.

#define UNITS 1024
#define U3 3072
#define BATCH 128
#define TSTEPS 256

typedef _Float16 h16;
typedef __attribute__((ext_vector_type(8))) _Float16 h16x8;
typedef __attribute__((ext_vector_type(4))) _Float16 h16x4;
typedef __attribute__((ext_vector_type(4))) float f32x4;
typedef __attribute__((ext_vector_type(4))) unsigned int u32x4;

#define GAS __attribute__((address_space(1)))
#define LAS __attribute__((address_space(3)))
#define ASYNC16(g, l) __builtin_amdgcn_global_load_lds((const GAS unsigned int*)(g), (LAS unsigned int*)(l), 16, 0, 0)

__device__ __forceinline__ float sigmf(float x) { return 1.0f / (1.0f + __expf(-x)); }
__device__ __forceinline__ float tanhf_fast(float x) { return 2.0f / (1.0f + __expf(-2.0f * x)) - 1.0f; }

// input_seq [B,T,U] f32 -> x16 [T,B,U] f16  (t-major so per-step slices are contiguous)
__global__ void k_cvt_x(const float* __restrict__ x, h16* __restrict__ xo) {
  const int m = blockIdx.x;            // out row = t*128 + b
  const int t = m >> 7, b = m & 127;
  const int u = threadIdx.x << 2;
  const float4 v = *(const float4*)(x + (size_t)((b << 8) + t) * UNITS + u);
  h16x4 o; o[0] = (h16)v.x; o[1] = (h16)v.y; o[2] = (h16)v.z; o[3] = (h16)v.w;
  *(h16x4*)(xo + (size_t)m * UNITS + u) = o;
}

// src [3][1024][3072] f32 -> dst [3][3072][1024] f16 (transpose: K-contiguous "B^T" layout)
__global__ void k_trans(const float* __restrict__ src, h16* __restrict__ dst) {
  __shared__ float sT[32][33];
  const int l = blockIdx.z;
  const int n0 = blockIdx.x << 5, k0 = blockIdx.y << 5;
  const int tx = threadIdx.x, ty = threadIdx.y;   // 32 x 8
  const float* s = src + (size_t)l * UNITS * U3;
  h16* d = dst + (size_t)l * U3 * UNITS;
#pragma unroll
  for (int r = 0; r < 4; ++r)
    sT[ty + r * 8][tx] = s[(size_t)(k0 + ty + r * 8) * U3 + n0 + tx];
  __syncthreads();
#pragma unroll
  for (int r = 0; r < 4; ++r)
    d[(size_t)(n0 + ty + r * 8) * UNITS + k0 + tx] = (h16)sT[tx][ty + r * 8];
}

// initial_states [B,U,3] f32 -> h0 [3][B*U] f16
__global__ void k_cvt_h(const float* __restrict__ init, h16* __restrict__ h0) {
  const int idx = blockIdx.x * 256 + threadIdx.x;  // < 3*131072
  const int l = idx >> 17, r = idx & 131071;
  h0[idx] = (h16)init[(size_t)r * 3 + l];
}

__global__ void k_zero(int* __restrict__ p, int n) {
  const int i = blockIdx.x * 256 + threadIdx.x;
  if (i < n) p[i] = 0;
}

// C[M,3072] = A[M,1024] @ Bt[3072,1024]^T + bias  (all f16 in, f32 acc, f16 out)
// m97 structure: 128x128 tile, BK=32, 4 waves 2x2, global_load_lds width 16.
__global__ __launch_bounds__(256) void k_gemm_xw(
    const h16* __restrict__ A, const h16* __restrict__ Bt,
    const float* __restrict__ bias, h16* __restrict__ C) {
  __shared__ __align__(16) h16 sA[128 * 32];
  __shared__ __align__(16) h16 sB[128 * 32];
  const int tid = threadIdx.x;
  const int lane = tid & 63, wave = tid >> 6;
  const int wm = (wave & 1) << 6, wn = (wave >> 1) << 6;
  const int m0 = blockIdx.x << 7;
  const int n0 = blockIdx.y << 7;
  const int crow = tid >> 2, ck = (tid & 3) << 3;
  const int fm = lane & 15, fq = lane >> 4;
  f32x4 acc[4][4] = {};
  for (int k0 = 0; k0 < 1024; k0 += 32) {
    ASYNC16(A + (size_t)(m0 + crow) * 1024 + k0 + ck,      sA + wave * 512);
    ASYNC16(A + (size_t)(m0 + 64 + crow) * 1024 + k0 + ck, sA + 2048 + wave * 512);
    ASYNC16(Bt + (size_t)(n0 + crow) * 1024 + k0 + ck,      sB + wave * 512);
    ASYNC16(Bt + (size_t)(n0 + 64 + crow) * 1024 + k0 + ck, sB + 2048 + wave * 512);
    __syncthreads();
    h16x8 af[4], bfv[4];
#pragma unroll
    for (int i = 0; i < 4; ++i)
      af[i] = *(const h16x8*)(sA + (wm + i * 16 + fm) * 32 + fq * 8);
#pragma unroll
    for (int j = 0; j < 4; ++j)
      bfv[j] = *(const h16x8*)(sB + (wn + j * 16 + fm) * 32 + fq * 8);
#pragma unroll
    for (int i = 0; i < 4; ++i)
#pragma unroll
      for (int j = 0; j < 4; ++j)
        acc[i][j] = __builtin_amdgcn_mfma_f32_16x16x32_f16(af[i], bfv[j], acc[i][j], 0, 0, 0);
    __syncthreads();
  }
#pragma unroll
  for (int j = 0; j < 4; ++j) {
    const int col = n0 + wn + j * 16 + fm;
    const float bv = bias[col];
#pragma unroll
    for (int i = 0; i < 4; ++i) {
      const int row = m0 + wm + i * 16 + fq * 4;
#pragma unroll
      for (int r = 0; r < 4; ++r)
        C[(size_t)(row + r) * U3 + col] = (h16)(acc[i][j][r] + bv);
    }
  }
}

// Persistent recurrence kernel, one launch per layer (all 256 steps inside).
// 256 blocks x 128 threads. Block b: col-group c=b&63 (16 h-cols), row-group
// rg=b>>6 (32 rows); wave w owns 16 rows. U^T slice (96KB) LDS-resident.
// hist[s] (= y[s], in the x16 region) is the rolling h buffer: producers
// write it with sc1 (agent write-through); consumers read it with PLAIN
// cached loads -- legal because each slot's lines are never cached anywhere
// before their unique write (entry fence kills pre-epoch lines).
// Sync: per-(rg,step) agent atomic counter + single broadcast sc1 poll.
__global__ __launch_bounds__(128, 1) void k_rec(
    const h16* __restrict__ Ut,     // [3072][1024] this layer
    const float* __restrict__ b1,   // [3072] recurrent bias
    const h16* __restrict__ xw,     // [T*128][3072]
    const h16* __restrict__ h0l,    // [128][1024] initial state
    h16* __restrict__ hist,         // [T][128][1024] rolling h history (x16)
    float* __restrict__ yf,         // f32 out y region or null (layer 2)
    float* __restrict__ st,         // d_out states + l (stride 3)
    int* __restrict__ cnt,          // [4][256] step counters (accumulating)
    const int tgt) {                // = 128*(l+1)
  __shared__ __align__(16) h16 sU[49152];   // 96KB: [32 kk][3 g][64 lane][8]
  // Invalidate pre-epoch L1/L2 lines (prev layer's hist at same addresses,
  // GEMM-era xw/x16 copies). Once per block; off the per-step chain.
  __builtin_amdgcn_fence(__ATOMIC_ACQUIRE, "agent");
  const int tid = threadIdx.x;
  const int lane = tid & 63, w = tid >> 6;
  const int b = blockIdx.x;
  const int c = b & 63, rg = b >> 6;
  const int c0 = c << 4;
  const int fm = lane & 15, fq = lane >> 4;

  // ---- stage U^T slice into LDS once ----
#pragma unroll
  for (int kk = 0; kk < 32; ++kk) {
#pragma unroll
    for (int g = 0; g < 3; ++g) {
      const int i = kk * 3 + g;
      if ((i & 1) == w)
        ASYNC16(Ut + (size_t)((g << 10) + c0 + fm) * 1024 + (kk << 5) + (fq << 3),
                sU + (size_t)i * 512);
    }
  }
  const int col = c0 + fm;
  const float bz = b1[col], br = b1[1024 + col], bh = b1[2048 + col];
  const int r0 = (rg << 5) + (w << 4);     // wave's first row
  const int rowA = r0 + fm;                // A-frag row for this lane
  const int rQ = r0 + (fq << 2);           // first of this lane's 4 C-rows
  int* cbase = cnt + (rg << 8);

  // ---- prefetch xw for step 0 (12 ushorts into regs) ----
  unsigned int xwb[12];
  {
    const h16* xq = xw + (size_t)rQ * U3 + col;
#pragma unroll
    for (int r = 0; r < 4; ++r) {
      const h16* xa = xq + (size_t)r * U3;
      const h16* xb2 = xa + 2048;
      asm volatile("global_load_ushort %0, %1, off"             : "=v"(xwb[r * 3 + 0]) : "v"(xa));
      asm volatile("global_load_ushort %0, %1, off offset:2048" : "=v"(xwb[r * 3 + 1]) : "v"(xa));
      asm volatile("global_load_ushort %0, %1, off"             : "=v"(xwb[r * 3 + 2]) : "v"(xb2));
    }
  }
  __syncthreads();   // drains ASYNC16 + prefetch (vmcnt 0 at loop entry)

  for (int s = 0; s < TSTEPS; ++s) {
    // ---- wait for own row-group's previous step (broadcast agent poll) ----
    if (s > 0) {
      const int* cp = cbase + s - 1;
      int f;
      do {
        asm volatile("global_load_dword %0, %1, off sc1\n\ts_waitcnt vmcnt(0)"
                     : "=v"(f) : "v"(cp) : "memory");
      } while (f < tgt);
    }
    const h16* hin = (s == 0) ? h0l : hist + (size_t)(s - 1) * 131072;

    // ---- issue 36 loads: 32 A + 4 hp, all PLAIN (L2-shared per XCD) ----
    u32x4 raw[32];
    const h16* Ab = hin + (size_t)rowA * 1024 + (fq << 3);
#pragma unroll
    for (int kk = 0; kk < 32; ++kk)
      asm volatile("global_load_dwordx4 %0, %1, off offset:%2"
                   : "=v"(raw[kk]) : "v"(Ab), "n"(kk * 64));
    unsigned int hpu[4];
    const h16* hqa = hin + (size_t)rQ * 1024 + col;
    const h16* hqb = hqa + 2048;  // +2 rows
    asm volatile("global_load_ushort %0, %1, off"             : "=v"(hpu[0]) : "v"(hqa));
    asm volatile("global_load_ushort %0, %1, off offset:2048" : "=v"(hpu[1]) : "v"(hqa));
    asm volatile("global_load_ushort %0, %1, off"             : "=v"(hpu[2]) : "v"(hqb));
    asm volatile("global_load_ushort %0, %1, off offset:2048" : "=v"(hpu[3]) : "v"(hqb));

    // ---- K-loop: 4 chunks of 8 kk, gated on A arrival by counted vmcnt ----
    f32x4 a0 = {}, a1 = {}, a2 = {};
#pragma unroll
    for (int ch = 0; ch < 4; ++ch) {
      if (ch == 0) asm volatile("s_waitcnt vmcnt(28)" ::: "memory");
      if (ch == 1) asm volatile("s_waitcnt vmcnt(20)" ::: "memory");
      if (ch == 2) asm volatile("s_waitcnt vmcnt(12)" ::: "memory");
      if (ch == 3) asm volatile("s_waitcnt vmcnt(4)"  ::: "memory");
      __builtin_amdgcn_sched_barrier(0);   // rule #18: keep MFMA below the wait
#pragma unroll
      for (int kk = ch * 8; kk < ch * 8 + 8; ++kk) {
        union { u32x4 u; h16x8 h; } ac; ac.u = raw[kk];
        const h16* bb = sU + (size_t)(kk * 3) * 512 + (lane << 3);
        const h16x8 vz = *(const h16x8*)(bb);
        const h16x8 vr = *(const h16x8*)(bb + 512);
        const h16x8 vh = *(const h16x8*)(bb + 1024);
        a0 = __builtin_amdgcn_mfma_f32_16x16x32_f16(ac.h, vz, a0, 0, 0, 0);
        a1 = __builtin_amdgcn_mfma_f32_16x16x32_f16(ac.h, vr, a1, 0, 0, 0);
        a2 = __builtin_amdgcn_mfma_f32_16x16x32_f16(ac.h, vh, a2, 0, 0, 0);
      }
    }
    asm volatile("s_waitcnt vmcnt(0)" ::: "memory");   // hp arrived
    __builtin_amdgcn_sched_barrier(0);

    // ---- gates (xw from regs, prefetched last step) ----
    h16* so = hist + (size_t)s * 131072 + (size_t)rQ * 1024 + col;
    float hn[4];
#pragma unroll
    for (int r = 0; r < 4; ++r) {
      union { unsigned short u; h16 h; } cv;
      cv.u = (unsigned short)hpu[r];         const float hp = (float)cv.h;
      cv.u = (unsigned short)xwb[r * 3 + 0]; const float xz = (float)cv.h;
      cv.u = (unsigned short)xwb[r * 3 + 1]; const float xr = (float)cv.h;
      cv.u = (unsigned short)xwb[r * 3 + 2]; const float xh = (float)cv.h;
      const float z   = sigmf(xz + a0[r] + bz);
      const float rgt = sigmf(xr + a1[r] + br);
      const float hh  = tanhf_fast(xh + rgt * (a2[r] + bh));
      hn[r] = z * hp + (1.0f - z) * hh;
      union { unsigned short u; h16 h; } ov; ov.h = (h16)hn[r];
      const unsigned int ob = ov.u;
      if (r == 0) asm volatile("global_store_short %0, %1, off sc1"             :: "v"(so), "v"(ob) : "memory");
      if (r == 1) asm volatile("global_store_short %0, %1, off offset:2048 sc1" :: "v"(so), "v"(ob) : "memory");
      if (r == 2) asm volatile("global_store_short %0, %1, off sc1"             :: "v"(so + 2048), "v"(ob) : "memory");
      if (r == 3) asm volatile("global_store_short %0, %1, off offset:2048 sc1" :: "v"(so + 2048), "v"(ob) : "memory");
    }

    // ---- prefetch xw for step s+1 (lands during next poll + K-loop) ----
    {
      const int sn = (s + 1) & 255;
      const h16* xq = xw + (size_t)(sn * 128 + rQ) * U3 + col;
#pragma unroll
      for (int r = 0; r < 4; ++r) {
        const h16* xa = xq + (size_t)r * U3;
        const h16* xb2 = xa + 2048;
        asm volatile("global_load_ushort %0, %1, off"             : "=v"(xwb[r * 3 + 0]) : "v"(xa));
        asm volatile("global_load_ushort %0, %1, off offset:2048" : "=v"(xwb[r * 3 + 1]) : "v"(xa));
        asm volatile("global_load_ushort %0, %1, off"             : "=v"(xwb[r * 3 + 2]) : "v"(xb2));
      }
    }
    // stores (issued before the 12 prefetch loads) acked at MALL:
    asm volatile("s_waitcnt vmcnt(12)" ::: "memory");
    if (lane == 0)
      (void)__hip_atomic_fetch_add(cbase + s, 1, __ATOMIC_RELAXED,
                                   __HIP_MEMORY_SCOPE_AGENT);
    // ---- non-protocol stores AFTER the post ----
    if (yf) {
#pragma unroll
      for (int r = 0; r < 4; ++r)
        yf[(size_t)((rQ + r) * 256 + s) * 1024 + col] = hn[r];
    }
    if (s == 255) {
#pragma unroll
      for (int r = 0; r < 4; ++r)
        st[(size_t)((rQ + r) * 1024 + col) * 3] = hn[r];
    }
  }
}

extern "C" void kernel_launch(void* const* d_in, const int* in_sizes, int n_in,
                              void* d_out, int out_size, void* d_ws, size_t ws_size,
                              hipStream_t stream) {
  const float* x_in  = (const float*)d_in[0];   // [128,256,1024]
  const float* h0_in = (const float*)d_in[1];   // [128,1024,3]
  const float* W     = (const float*)d_in[2];   // [3,1024,3072]
  const float* U     = (const float*)d_in[3];   // [3,1024,3072]
  const float* bias  = (const float*)d_in[4];   // [3,2,3072]
  float* out = (float*)d_out;

  char* ws = (char*)d_ws;
  h16* x16 = (h16*)(ws);                         // 67,108,864 B   [T,B,U] input / h-history
  h16* xw  = (h16*)(ws + 67108864);              // 201,326,592 B  [T,B,3U]
  h16* Wt  = (h16*)(ws + 268435456);             // 18,874,368 B   [3][3072][1024]
  h16* Ut  = (h16*)(ws + 287309824);             // 18,874,368 B   [3][3072][1024]
  h16* h0b = (h16*)(ws + 306184192);             // 786,432 B      [3][128*1024]
  int* cnt = (int*)(ws + 306970624);             // 4,096 B        [4][256] counters

  k_cvt_x<<<TSTEPS * BATCH, 256, 0, stream>>>(x_in, x16);
  k_trans<<<dim3(96, 32, 3), dim3(32, 8), 0, stream>>>(W, Wt);
  k_trans<<<dim3(96, 32, 3), dim3(32, 8), 0, stream>>>(U, Ut);
  k_cvt_h<<<1536, 256, 0, stream>>>(h0_in, h0b);
  k_zero<<<4, 256, 0, stream>>>(cnt, 1024);      // counters accumulate across layers

  for (int l = 0; l < 3; ++l) {
    const float* b0 = bias + (size_t)l * 6144;
    const float* b1 = bias + (size_t)l * 6144 + 3072;
    // GEMM reads x16 = (l==0 ? converted input : previous layer's h-history)
    k_gemm_xw<<<dim3(256, 24), 256, 0, stream>>>(x16, Wt + (size_t)l * U3 * UNITS, b0, xw);
    float* yfp = (l == 2) ? out : nullptr;
    float* stp = out + 33554432 + l;
    k_rec<<<256, 128, 0, stream>>>(Ut + (size_t)l * U3 * UNITS, b1, xw,
                                   h0b + (size_t)l * BATCH * UNITS,
                                   x16, yfp, stp, cnt, 128 * (l + 1));
  }
}